// Round 16
// baseline (96.155 us; speedup 1.0000x reference)
//
#include <hip/hip_runtime.h>
#include <math.h>

typedef short bf16x8 __attribute__((ext_vector_type(8)));
typedef float f32x4  __attribute__((ext_vector_type(4)));

constexpr int   B_    = 4;
constexpr int   N_    = 2048;
constexpr int   INF_  = 256;
constexpr int   OUTF_ = 128;
constexpr float LAMBDA_INIT_ = 0.35550906759096926f;
constexpr float OUT_SCALE_   = 0.64449093240903074f;   // 1 - LAMBDA_INIT
constexpr float EPS_         = 1e-5f;
constexpr float LOG2E_       = 1.44269504088896340736f;

__device__ inline unsigned short f2bf(float x) {
  unsigned u = __float_as_uint(x);
  u += 0x7fffu + ((u >> 16) & 1u);          // round-to-nearest-even
  return (unsigned short)(u >> 16);
}
__device__ inline unsigned pack2(float a, float b) {
  return (unsigned)f2bf(a) | ((unsigned)f2bf(b) << 16);
}

// Canonical wave64 sum-reduce on the VALU via DPP (LLVM atomic-optimizer sequence).
// Returns the total (uniform, via readlane 63). All-positive fp32 inputs here.
__device__ inline float waveRedSumDpp(float v) {
  v += __int_as_float(__builtin_amdgcn_update_dpp(0, __float_as_int(v), 0x111, 0xf, 0xf, true)); // row_shr:1
  v += __int_as_float(__builtin_amdgcn_update_dpp(0, __float_as_int(v), 0x112, 0xf, 0xf, true)); // row_shr:2
  v += __int_as_float(__builtin_amdgcn_update_dpp(0, __float_as_int(v), 0x114, 0xf, 0xf, true)); // row_shr:4
  v += __int_as_float(__builtin_amdgcn_update_dpp(0, __float_as_int(v), 0x118, 0xf, 0xf, true)); // row_shr:8
  v += __int_as_float(__builtin_amdgcn_update_dpp(0, __float_as_int(v), 0x142, 0xa, 0xf, true)); // row_bcast:15
  v += __int_as_float(__builtin_amdgcn_update_dpp(0, __float_as_int(v), 0x143, 0xc, 0xf, true)); // row_bcast:31
  return __int_as_float(__builtin_amdgcn_readlane(__float_as_int(v), 63));
}

// ---------------- Kernel A: tiny scalars (rel scores + lambda), log2e-scaled ----------------
__global__ void scalars_kernel(const float* __restrict__ rel_emb,
                               const float* __restrict__ a_rel_pos,
                               const float* __restrict__ a_rel_neg,
                               const float* __restrict__ ll1, const float* __restrict__ lr1,
                               const float* __restrict__ ll2, const float* __restrict__ lr2,
                               float* __restrict__ scal) {
  int lane = threadIdx.x;  // 64 threads, 1 wave
  float p1 = ll1[lane] * lr1[lane];
  float p2 = ll2[lane] * lr2[lane];
  #pragma unroll
  for (int off = 32; off; off >>= 1) { p1 += __shfl_xor(p1, off); p2 += __shfl_xor(p2, off); }
  if (lane == 0) scal[12] = expf(p1) - expf(p2) + LAMBDA_INIT_;   // lam: NOT scaled
  if (lane < 6) {
    float sp = 0.f, sn = 0.f;
    for (int k = 0; k < 10; ++k) {
      float rv = rel_emb[lane * 10 + k];
      sp += rv * a_rel_pos[k];
      sn += rv * a_rel_neg[k];
    }
    scal[lane]     = sp * LOG2E_;
    scal[6 + lane] = sn * LOG2E_;
  }
}

// ---------------- Kernel B: Wh GEMM -> bf16 transposed copy + fused dots (r12-passing) ----------------
__global__ __launch_bounds__(256) void wh_dots_kernel(
    const float* __restrict__ h, const float* __restrict__ W,
    const float* __restrict__ alp, const float* __restrict__ arp,
    const float* __restrict__ aln, const float* __restrict__ arn,
    unsigned short* __restrict__ WhvT,
    float* __restrict__ lposv, float* __restrict__ rposv,
    float* __restrict__ lnegv, float* __restrict__ rnegv) {
  __shared__ __align__(16) float hT[INF_][20];
  const int t = threadIdx.x;
  const size_t row0 = (size_t)blockIdx.x * 16;
  #pragma unroll
  for (int i = 0; i < 16; ++i) hT[t][i] = h[(row0 + i) * INF_ + t];
  __syncthreads();
  const int c  = t & 127;
  const int rg = t >> 7;
  float acc[8] = {0.f, 0.f, 0.f, 0.f, 0.f, 0.f, 0.f, 0.f};
  #pragma unroll 4
  for (int k = 0; k < INF_; ++k) {
    float wv = W[k * OUTF_ + c];
    const float4* hp = reinterpret_cast<const float4*>(&hT[k][rg * 8]);
    float4 h0 = hp[0], h1 = hp[1];
    acc[0] += h0.x * wv; acc[1] += h0.y * wv; acc[2] += h0.z * wv; acc[3] += h0.w * wv;
    acc[4] += h1.x * wv; acc[5] += h1.y * wv; acc[6] += h1.z * wv; acc[7] += h1.w * wv;
  }
  uint4 pk;
  pk.x = pack2(acc[0], acc[1]); pk.y = pack2(acc[2], acc[3]);
  pk.z = pack2(acc[4], acc[5]); pk.w = pack2(acc[6], acc[7]);
  const int b  = (int)(row0 >> 11);
  const int n0 = (int)(row0 & 2047) + rg * 8;
  *reinterpret_cast<uint4*>(WhvT + ((size_t)b * OUTF_ + c) * N_ + n0) = pk;

  // ---- fused dots: wave wv covers channels (wv&1)*64..+63 of rows rg*8..rg*8+7
  const int lane = t & 63;
  const int wv   = t >> 6;
  const bool pos = (wv & 1) == 0;      // even wave: ch 0..63 (pos half); odd: 64..127 (neg)
  const float al = pos ? alp[lane] : aln[lane];
  const float ar = pos ? arp[lane] : arn[lane];
  float sl[8], sr2[8];
  #pragma unroll
  for (int r = 0; r < 8; ++r) { sl[r] = acc[r] * al; sr2[r] = acc[r] * ar; }
  #pragma unroll
  for (int off = 32; off; off >>= 1) {
    #pragma unroll
    for (int r = 0; r < 8; ++r) {
      sl[r]  += __shfl_xor(sl[r],  off);
      sr2[r] += __shfl_xor(sr2[r], off);
    }
  }
  if (lane == 0) {
    #pragma unroll
    for (int r = 0; r < 8; ++r) {
      const int node = (int)row0 + rg * 8 + r;
      if (pos) { lposv[node] = sl[r] * LOG2E_; rposv[node] = sr2[r] * LOG2E_; }
      else     { lnegv[node] = sl[r] * LOG2E_; rnegv[node] = sr2[r] * LOG2E_; }
    }
  }
}

// ---------------- Kernel D1: attention, 8 rows/block, DS-pipe-light ----------------
// 1024 blocks x 512 threads; thread t covers j = t*4..t*4+3 for 8 rows.
// rel-score via VALU cndmask chain (no bpermute); wave reduce via DPP (VALU);
// cross-wave tail via 4 float4 LDS reads. Same math values as r14's attn_v4.
__global__ __launch_bounds__(512) void attn_v5(
    const int* __restrict__ adj,
    const float* __restrict__ lposv, const float* __restrict__ rposv,
    const float* __restrict__ lnegv, const float* __restrict__ rnegv,
    const float* __restrict__ scal, float* __restrict__ out1) {
  __shared__ __align__(16) float sums[2][16];   // [buf][P:0..7 | N:8..15]
  const int t = threadIdx.x;
  const int lane = t & 63;
  const int wv = t >> 6;
  const int flat0 = blockIdx.x * 8;   // b*N + i base
  const int b = flat0 >> 11;

  const float lam = scal[12];
  const float rP1 = scal[1], rP2 = scal[2], rP3 = scal[3], rP4 = scal[4], rP5 = scal[5];
  const float rN1 = scal[7], rN2 = scal[8], rN3 = scal[9], rN4 = scal[10], rN5 = scal[11];

  const int j0 = t * 4;
  float4 rp4 = *reinterpret_cast<const float4*>(rposv + b * N_ + j0);
  float4 rn4 = *reinterpret_cast<const float4*>(rnegv + b * N_ + j0);
  const float rp[4] = {rp4.x, rp4.y, rp4.z, rp4.w};
  const float rn[4] = {rn4.x, rn4.y, rn4.z, rn4.w};

  int4 avN = *reinterpret_cast<const int4*>(adj + (size_t)flat0 * N_ + j0);

  #pragma unroll
  for (int r = 0; r < 8; ++r) {
    const int flat = flat0 + r;
    const int4 av4 = avN;
    if (r < 7)
      avN = *reinterpret_cast<const int4*>(adj + (size_t)(flat + 1) * N_ + j0);
    const float lP = lposv[flat];
    const float lN = lnegv[flat];
    int av[4] = {av4.x, av4.y, av4.z, av4.w};

    float p[4], n[4];
    #pragma unroll
    for (int q = 0; q < 4; ++q) {
      const int a = av[q];
      float rsp = (a == 1) ? rP1 : (a == 2) ? rP2 : (a == 3) ? rP3 : (a == 4) ? rP4 : rP5;
      float rsn = (a == 1) ? rN1 : (a == 2) ? rN2 : (a == 3) ? rN3 : (a == 4) ? rN4 : rN5;
      float e  = lP + rp[q] + rsp;
      float en = lN + rn[q] + rsn;
      e  = fmaxf(e, 0.2f * e);                 // leaky (pos scale commutes with log2e)
      en = fmaxf(en, 0.2f * en);
      float pe = __builtin_amdgcn_exp2f(e);
      float ne = __builtin_amdgcn_exp2f(en);
      if (a == 0) { pe = 0.f; ne = 0.f; }      // mask (== exp2(-1e30) = 0 before)
      p[q] = pe; n[q] = ne;
    }
    float sP = (p[0] + p[1]) + (p[2] + p[3]);
    float sN = (n[0] + n[1]) + (n[2] + n[3]);
    const float totP = waveRedSumDpp(sP);      // VALU-only reduce
    const float totN = waveRedSumDpp(sN);
    const int bf = r & 1;
    if (lane == 0) { sums[bf][wv] = totP; sums[bf][8 + wv] = totN; }
    __syncthreads();
    const float4 pa = *reinterpret_cast<const float4*>(&sums[bf][0]);
    const float4 pb = *reinterpret_cast<const float4*>(&sums[bf][4]);
    const float4 na = *reinterpret_cast<const float4*>(&sums[bf][8]);
    const float4 nb = *reinterpret_cast<const float4*>(&sums[bf][12]);
    const float vP = ((pa.x + pa.y) + (pa.z + pa.w)) + ((pb.x + pb.y) + (pb.z + pb.w));
    const float vN = ((na.x + na.y) + (na.z + na.w)) + ((nb.x + nb.y) + (nb.z + nb.w));
    const float s1 = 1.f / vP;
    const float s2 = -lam / vN;

    float a[4];
    #pragma unroll
    for (int q = 0; q < 4; ++q) a[q] = p[q] * s1 + n[q] * s2;
    float* o1 = out1 + (size_t)flat * N_ + j0;
    *reinterpret_cast<float4*>(o1) = make_float4(a[0], a[1], a[2], a[3]);
  }
}

// ---------------- Kernel D2: PV via MFMA, deep prefetch (r15-passing pv_v5c, unchanged) ----------------
__global__ __launch_bounds__(512, 4) void pv_v5c(
    const float* __restrict__ attn, const unsigned short* __restrict__ WhvT,
    const float* __restrict__ gamma, const float* __restrict__ beta,
    float* __restrict__ out0) {
  __shared__ __align__(16) uint4 A4[2][16 * 32];   // [buf][row*32 + unit(16B)], 16KB
  __shared__ __align__(16) float hp[16][132];
  const int t = threadIdx.x;
  const int lane = t & 63;
  const int w = t >> 6;
  const int bi = blockIdx.x;
  const int b  = bi >> 7;
  const int i0 = (bi & 127) * 16;

  const int sr = t >> 5;
  const int sj = t & 31;
  const float4* src4 = reinterpret_cast<const float4*>(
      attn + ((size_t)(b * N_ + i0 + sr)) * N_ + sj * 8);
  const int swz = sr & 7;
  const int ui = sr * 32 + (sj ^ swz);

  const int bl  = lane & 15;   // A row / B ch within tile
  const int kg  = lane >> 4;   // k-group
  const int ch  = w * 16 + bl;
  const unsigned short* Bp = WhvT + ((size_t)b * OUTF_ + ch) * N_ + kg * 8;
  f32x4 acc0 = {0.f, 0.f, 0.f, 0.f};   // even chunks
  f32x4 acc1 = {0.f, 0.f, 0.f, 0.f};   // odd chunks
  const int arow = bl * 32;
  const int aswz = bl & 7;

  bf16x8 bBuf[2][8];           // parity-indexed B fragments

  {
    float4 s0 = src4[0], s1 = src4[1];
    uint4 u;
    u.x = pack2(s0.x, s0.y); u.y = pack2(s0.z, s0.w);
    u.z = pack2(s1.x, s1.y); u.w = pack2(s1.z, s1.w);
    A4[0][ui] = u;
  }
  float4 n0 = src4[64], n1 = src4[65];          // A(1) data in regs
  #pragma unroll
  for (int kk = 0; kk < 8; ++kk)
    bBuf[0][kk] = *reinterpret_cast<const bf16x8*>(Bp + kk * 32);
  __syncthreads();

  #pragma unroll
  for (int c = 0; c < 8; ++c) {
    const int cur = c & 1;
    float4 m0, m1;                               // A(c+2) issue
    if (c < 6) { m0 = src4[(c + 2) * 64]; m1 = src4[(c + 2) * 64 + 1]; }
    if (c < 7) {                                 // B(c+1) issue into other parity
      #pragma unroll
      for (int kk = 0; kk < 8; ++kk)
        bBuf[cur ^ 1][kk] = *reinterpret_cast<const bf16x8*>(Bp + (c + 1) * 256 + kk * 32);
    }
    #pragma unroll
    for (int kk = 0; kk < 8; ++kk) {
      bf16x8 a = *reinterpret_cast<const bf16x8*>(&A4[cur][arow + ((kk * 4 + kg) ^ aswz)]);
      if (cur == 0) acc0 = __builtin_amdgcn_mfma_f32_16x16x32_bf16(a, bBuf[0][kk], acc0, 0, 0, 0);
      else          acc1 = __builtin_amdgcn_mfma_f32_16x16x32_bf16(a, bBuf[1][kk], acc1, 0, 0, 0);
    }
    if (c < 7) {                                 // write A(c+1) to LDS
      uint4 u;
      u.x = pack2(n0.x, n0.y); u.y = pack2(n0.z, n0.w);
      u.z = pack2(n1.x, n1.y); u.w = pack2(n1.z, n1.w);
      A4[cur ^ 1][ui] = u;
    }
    n0 = m0; n1 = m1;
    __syncthreads();
  }

  #pragma unroll
  for (int q = 0; q < 4; ++q) hp[kg * 4 + q][ch] = acc0[q] + acc1[q];
  __syncthreads();

  const int row = t >> 5;
  const int c0  = t & 31;
  float v[4], s = 0.f, sq = 0.f;
  #pragma unroll
  for (int e = 0; e < 4; ++e) {
    v[e] = hp[row][c0 + e * 32];
    s += v[e]; sq += v[e] * v[e];
  }
  #pragma unroll
  for (int off = 16; off; off >>= 1) { s += __shfl_xor(s, off); sq += __shfl_xor(sq, off); }
  const float mu  = s  * (1.f / 128.f);
  const float var = sq * (1.f / 128.f) - mu * mu;
  const float inv = rsqrtf(var + EPS_);
  float* orow = out0 + ((size_t)(b * N_ + i0 + row)) * OUTF_;
  #pragma unroll
  for (int e = 0; e < 4; ++e) {
    const int chh = c0 + e * 32;
    float y = (v[e] - mu) * inv * gamma[chh] + beta[chh];
    y *= OUT_SCALE_;
    orow[chh] = 0.5f * y * (1.f + erff(y * 0.70710678118654752f));
  }
}

extern "C" void kernel_launch(void* const* d_in, const int* in_sizes, int n_in,
                              void* d_out, int out_size, void* d_ws, size_t ws_size,
                              hipStream_t stream) {
  (void)in_sizes; (void)n_in; (void)out_size; (void)ws_size;
  const float* h        = (const float*)d_in[0];
  const int*   adj      = (const int*)d_in[1];
  const float* W        = (const float*)d_in[2];
  const float* alp      = (const float*)d_in[3];
  const float* arp      = (const float*)d_in[4];
  const float* aln      = (const float*)d_in[5];
  const float* arn      = (const float*)d_in[6];
  const float* rel_emb  = (const float*)d_in[7];
  const float* a_rel_p  = (const float*)d_in[8];
  const float* a_rel_n  = (const float*)d_in[9];
  const float* ll1      = (const float*)d_in[10];
  const float* lr1      = (const float*)d_in[11];
  const float* ll2      = (const float*)d_in[12];
  const float* lr2      = (const float*)d_in[13];
  const float* gamma    = (const float*)d_in[14];
  const float* beta     = (const float*)d_in[15];

  float* out0 = (float*)d_out;                          // gelu(h'): B*N*OUTF
  float* out1 = out0 + (size_t)B_ * N_ * OUTF_;         // attention: B*N*N

  float* ws    = (float*)d_ws;
  float* scal  = ws;                    // 32 floats
  float* lposv = ws + 32;               // B*N
  float* rposv = lposv + B_ * N_;
  float* lnegv = rposv + B_ * N_;
  float* rnegv = lnegv + B_ * N_;
  unsigned short* WhvT = (unsigned short*)(rnegv + B_ * N_);   // [B][OUTF][N] bf16

  scalars_kernel<<<1, 64, 0, stream>>>(rel_emb, a_rel_p, a_rel_n, ll1, lr1, ll2, lr2, scal);
  wh_dots_kernel<<<(B_ * N_) / 16, 256, 0, stream>>>(h, W, alp, arp, aln, arn,
                                                     WhvT, lposv, rposv, lnegv, rnegv);
  attn_v5<<<(B_ * N_) / 8, 512, 0, stream>>>(adj, lposv, rposv, lnegv, rnegv, scal, out1);
  pv_v5c<<<B_ * (N_ / 16), 512, 0, stream>>>(out1, WhvT, gamma, beta, out0);
}

// Round 17
// 89.390 us; speedup vs baseline: 1.0757x; 1.0757x over previous
//
#include <hip/hip_runtime.h>
#include <math.h>

typedef short bf16x8 __attribute__((ext_vector_type(8)));
typedef float f32x4  __attribute__((ext_vector_type(4)));

constexpr int   B_    = 4;
constexpr int   N_    = 2048;
constexpr int   INF_  = 256;
constexpr int   OUTF_ = 128;
constexpr float LAMBDA_INIT_ = 0.35550906759096926f;
constexpr float OUT_SCALE_   = 0.64449093240903074f;   // 1 - LAMBDA_INIT
constexpr float EPS_         = 1e-5f;
constexpr float LOG2E_       = 1.44269504088896340736f;

__device__ inline unsigned short f2bf(float x) {
  unsigned u = __float_as_uint(x);
  u += 0x7fffu + ((u >> 16) & 1u);          // round-to-nearest-even
  return (unsigned short)(u >> 16);
}
__device__ inline unsigned pack2(float a, float b) {
  return (unsigned)f2bf(a) | ((unsigned)f2bf(b) << 16);
}

// ---------------- Kernel A: tiny scalars (rel scores + lambda), log2e-scaled ----------------
__global__ void scalars_kernel(const float* __restrict__ rel_emb,
                               const float* __restrict__ a_rel_pos,
                               const float* __restrict__ a_rel_neg,
                               const float* __restrict__ ll1, const float* __restrict__ lr1,
                               const float* __restrict__ ll2, const float* __restrict__ lr2,
                               float* __restrict__ scal) {
  int lane = threadIdx.x;  // 64 threads, 1 wave
  float p1 = ll1[lane] * lr1[lane];
  float p2 = ll2[lane] * lr2[lane];
  #pragma unroll
  for (int off = 32; off; off >>= 1) { p1 += __shfl_xor(p1, off); p2 += __shfl_xor(p2, off); }
  if (lane == 0) scal[12] = expf(p1) - expf(p2) + LAMBDA_INIT_;   // lam: NOT scaled
  if (lane < 6) {
    float sp = 0.f, sn = 0.f;
    for (int k = 0; k < 10; ++k) {
      float rv = rel_emb[lane * 10 + k];
      sp += rv * a_rel_pos[k];
      sn += rv * a_rel_neg[k];
    }
    scal[lane]     = sp * LOG2E_;
    scal[6 + lane] = sn * LOG2E_;
  }
}

// ---------------- Kernel B: Wh GEMM -> bf16 transposed copy + fused dots (r12-passing) ----------------
__global__ __launch_bounds__(256) void wh_dots_kernel(
    const float* __restrict__ h, const float* __restrict__ W,
    const float* __restrict__ alp, const float* __restrict__ arp,
    const float* __restrict__ aln, const float* __restrict__ arn,
    unsigned short* __restrict__ WhvT,
    float* __restrict__ lposv, float* __restrict__ rposv,
    float* __restrict__ lnegv, float* __restrict__ rnegv) {
  __shared__ __align__(16) float hT[INF_][20];
  const int t = threadIdx.x;
  const size_t row0 = (size_t)blockIdx.x * 16;
  #pragma unroll
  for (int i = 0; i < 16; ++i) hT[t][i] = h[(row0 + i) * INF_ + t];
  __syncthreads();
  const int c  = t & 127;
  const int rg = t >> 7;
  float acc[8] = {0.f, 0.f, 0.f, 0.f, 0.f, 0.f, 0.f, 0.f};
  #pragma unroll 4
  for (int k = 0; k < INF_; ++k) {
    float wv = W[k * OUTF_ + c];
    const float4* hp = reinterpret_cast<const float4*>(&hT[k][rg * 8]);
    float4 h0 = hp[0], h1 = hp[1];
    acc[0] += h0.x * wv; acc[1] += h0.y * wv; acc[2] += h0.z * wv; acc[3] += h0.w * wv;
    acc[4] += h1.x * wv; acc[5] += h1.y * wv; acc[6] += h1.z * wv; acc[7] += h1.w * wv;
  }
  uint4 pk;
  pk.x = pack2(acc[0], acc[1]); pk.y = pack2(acc[2], acc[3]);
  pk.z = pack2(acc[4], acc[5]); pk.w = pack2(acc[6], acc[7]);
  const int b  = (int)(row0 >> 11);
  const int n0 = (int)(row0 & 2047) + rg * 8;
  *reinterpret_cast<uint4*>(WhvT + ((size_t)b * OUTF_ + c) * N_ + n0) = pk;

  // ---- fused dots: wave wv covers channels (wv&1)*64..+63 of rows rg*8..rg*8+7
  const int lane = t & 63;
  const int wv   = t >> 6;
  const bool pos = (wv & 1) == 0;      // even wave: ch 0..63 (pos half); odd: 64..127 (neg)
  const float al = pos ? alp[lane] : aln[lane];
  const float ar = pos ? arp[lane] : arn[lane];
  float sl[8], sr2[8];
  #pragma unroll
  for (int r = 0; r < 8; ++r) { sl[r] = acc[r] * al; sr2[r] = acc[r] * ar; }
  #pragma unroll
  for (int off = 32; off; off >>= 1) {
    #pragma unroll
    for (int r = 0; r < 8; ++r) {
      sl[r]  += __shfl_xor(sl[r],  off);
      sr2[r] += __shfl_xor(sr2[r], off);
    }
  }
  if (lane == 0) {
    #pragma unroll
    for (int r = 0; r < 8; ++r) {
      const int node = (int)row0 + rg * 8 + r;
      if (pos) { lposv[node] = sl[r] * LOG2E_; rposv[node] = sr2[r] * LOG2E_; }
      else     { lnegv[node] = sl[r] * LOG2E_; rnegv[node] = sr2[r] * LOG2E_; }
    }
  }
}

// ---------------- Kernel D: fused attention + PV(MFMA) + LN + GELU ----------------
// 512 blocks x 512 threads. Block = 16 rows. Phase 1: attn_v4's per-row math
// (verbatim) writing out1 AND depositing bf16-packed A-frags into a 64KB LDS tile.
// Phase 2: pv_v5c's MFMA loop with A from LDS (no staging), B reg-prefetched.
// Row-15's LDS region doubles as the sums scratch (freed before row 15's write).
__global__ __launch_bounds__(512, 4) void fused_attn_pv(
    const int* __restrict__ adj,
    const float* __restrict__ lposv, const float* __restrict__ rposv,
    const float* __restrict__ lnegv, const float* __restrict__ rnegv,
    const float* __restrict__ scal, const unsigned short* __restrict__ WhvT,
    const float* __restrict__ gamma, const float* __restrict__ beta,
    float* __restrict__ out0, float* __restrict__ out1) {
  __shared__ __align__(16) uint4 A4[16 * 256];                  // 64KB A-tile
  float* scr = reinterpret_cast<float*>(&A4[15 * 256]);         // sums scratch (row-15 tail)
  float (*hp)[132] = reinterpret_cast<float (*)[132]>(A4);      // epilogue overlay

  const int t = threadIdx.x;
  const int lane = t & 63;
  const int wv = t >> 6;
  const int bi = blockIdx.x;
  const int b  = bi >> 7;
  const int i0 = (bi & 127) * 16;
  const int flat0 = b * N_ + i0;

  const float lam = scal[12];
  float srcP = -1.0e30f, srcN = -1.0e30f;
  if (lane >= 1 && lane <= 5) { srcP = scal[lane]; srcN = scal[6 + lane]; }
  const int iSrcP = __float_as_int(srcP);
  const int iSrcN = __float_as_int(srcN);

  const int j0 = t * 4;
  float4 rp4 = *reinterpret_cast<const float4*>(rposv + b * N_ + j0);
  float4 rn4 = *reinterpret_cast<const float4*>(rnegv + b * N_ + j0);
  const float rp[4] = {rp4.x, rp4.y, rp4.z, rp4.w};
  const float rn[4] = {rn4.x, rn4.y, rn4.z, rn4.w};

  // A-tile write coords: unit u = t>>1 (8 k's), half = t&1 (8B), per-chunk XOR swizzle
  const int wchunk = (t >> 1) >> 5;
  const int wloc   = (t >> 1) & 31;

  int4 avN = *reinterpret_cast<const int4*>(adj + (size_t)flat0 * N_ + j0);

  for (int r = 0; r < 16; ++r) {
    const int flat = flat0 + r;
    const int4 av4 = avN;
    if (r < 15)
      avN = *reinterpret_cast<const int4*>(adj + (size_t)(flat + 1) * N_ + j0);
    const float lP = lposv[flat];
    const float lN = lnegv[flat];
    int av[4] = {av4.x, av4.y, av4.z, av4.w};

    float p[4], n[4];
    #pragma unroll
    for (int q = 0; q < 4; ++q) {
      float rsp = __int_as_float(__builtin_amdgcn_ds_bpermute(av[q] << 2, iSrcP));
      float rsn = __int_as_float(__builtin_amdgcn_ds_bpermute(av[q] << 2, iSrcN));
      float e  = lP + rp[q] + rsp;
      float en = lN + rn[q] + rsn;
      e  = fmaxf(e, 0.2f * e);                 // leaky (pos scale commutes with log2e)
      en = fmaxf(en, 0.2f * en);
      p[q] = __builtin_amdgcn_exp2f(e);
      n[q] = __builtin_amdgcn_exp2f(en);
    }
    float sP = (p[0] + p[1]) + (p[2] + p[3]);
    float sN = (n[0] + n[1]) + (n[2] + n[3]);
    #pragma unroll
    for (int off = 32; off; off >>= 1) { sP += __shfl_xor(sP, off); sN += __shfl_xor(sN, off); }
    const int bf = r & 1;
    if (lane == 0) { scr[bf * 16 + wv] = sP; scr[bf * 16 + 8 + wv] = sN; }
    __syncthreads();
    float vP = scr[bf * 16 + (lane & 7)];
    vP += __shfl_xor(vP, 1); vP += __shfl_xor(vP, 2); vP += __shfl_xor(vP, 4);
    float vN = scr[bf * 16 + 8 + (lane & 7)];
    vN += __shfl_xor(vN, 1); vN += __shfl_xor(vN, 2); vN += __shfl_xor(vN, 4);
    const float s1 = 1.f / vP;
    const float s2 = -lam / vN;

    float a[4];
    #pragma unroll
    for (int q = 0; q < 4; ++q) a[q] = p[q] * s1 + n[q] * s2;
    float* o1 = out1 + (size_t)flat * N_ + j0;
    *reinterpret_cast<float4*>(o1) = make_float4(a[0], a[1], a[2], a[3]);

    if (r == 15) __syncthreads();   // drain scr reads before row-15 region is overwritten
    const int uidx = r * 256 + wchunk * 32 + (wloc ^ (r & 7));
    uint2 val;
    val.x = pack2(a[0], a[1]); val.y = pack2(a[2], a[3]);
    reinterpret_cast<uint2*>(A4)[uidx * 2 + (t & 1)] = val;
  }
  __syncthreads();   // A-tile complete

  // ---------------- phase 2: MFMA over full K, A from LDS, B reg-prefetched ----------------
  const int bl  = lane & 15;   // A row / B ch within tile
  const int kg  = lane >> 4;   // k-group
  const int ch  = wv * 16 + bl;
  const unsigned short* Bp = WhvT + ((size_t)b * OUTF_ + ch) * N_ + kg * 8;
  f32x4 acc0 = {0.f, 0.f, 0.f, 0.f};   // even chunks
  f32x4 acc1 = {0.f, 0.f, 0.f, 0.f};   // odd chunks
  const int arow = bl * 256;
  const int aswz = bl & 7;

  bf16x8 bBuf[2][8];
  #pragma unroll
  for (int kk = 0; kk < 8; ++kk)
    bBuf[0][kk] = *reinterpret_cast<const bf16x8*>(Bp + kk * 32);

  #pragma unroll
  for (int c = 0; c < 8; ++c) {
    const int cur = c & 1;
    if (c < 7) {
      #pragma unroll
      for (int kk = 0; kk < 8; ++kk)
        bBuf[cur ^ 1][kk] = *reinterpret_cast<const bf16x8*>(Bp + (c + 1) * 256 + kk * 32);
    }
    #pragma unroll
    for (int kk = 0; kk < 8; ++kk) {
      bf16x8 a = *reinterpret_cast<const bf16x8*>(&A4[arow + c * 32 + ((kk * 4 + kg) ^ aswz)]);
      if (cur == 0) acc0 = __builtin_amdgcn_mfma_f32_16x16x32_bf16(a, bBuf[0][kk], acc0, 0, 0, 0);
      else          acc1 = __builtin_amdgcn_mfma_f32_16x16x32_bf16(a, bBuf[1][kk], acc1, 0, 0, 0);
    }
  }
  __syncthreads();   // all A reads done; overlay hp

  #pragma unroll
  for (int q = 0; q < 4; ++q) hp[kg * 4 + q][ch] = acc0[q] + acc1[q];
  __syncthreads();

  const int row = t >> 5;
  const int c0  = t & 31;
  float v[4], s = 0.f, sq = 0.f;
  #pragma unroll
  for (int e = 0; e < 4; ++e) {
    v[e] = hp[row][c0 + e * 32];
    s += v[e]; sq += v[e] * v[e];
  }
  #pragma unroll
  for (int off = 16; off; off >>= 1) { s += __shfl_xor(s, off); sq += __shfl_xor(sq, off); }
  const float mu  = s  * (1.f / 128.f);
  const float var = sq * (1.f / 128.f) - mu * mu;
  const float inv = rsqrtf(var + EPS_);
  float* orow = out0 + ((size_t)(b * N_ + i0 + row)) * OUTF_;
  #pragma unroll
  for (int e = 0; e < 4; ++e) {
    const int chh = c0 + e * 32;
    float y = (v[e] - mu) * inv * gamma[chh] + beta[chh];
    y *= OUT_SCALE_;
    orow[chh] = 0.5f * y * (1.f + erff(y * 0.70710678118654752f));
  }
}

extern "C" void kernel_launch(void* const* d_in, const int* in_sizes, int n_in,
                              void* d_out, int out_size, void* d_ws, size_t ws_size,
                              hipStream_t stream) {
  (void)in_sizes; (void)n_in; (void)out_size; (void)ws_size;
  const float* h        = (const float*)d_in[0];
  const int*   adj      = (const int*)d_in[1];
  const float* W        = (const float*)d_in[2];
  const float* alp      = (const float*)d_in[3];
  const float* arp      = (const float*)d_in[4];
  const float* aln      = (const float*)d_in[5];
  const float* arn      = (const float*)d_in[6];
  const float* rel_emb  = (const float*)d_in[7];
  const float* a_rel_p  = (const float*)d_in[8];
  const float* a_rel_n  = (const float*)d_in[9];
  const float* ll1      = (const float*)d_in[10];
  const float* lr1      = (const float*)d_in[11];
  const float* ll2      = (const float*)d_in[12];
  const float* lr2      = (const float*)d_in[13];
  const float* gamma    = (const float*)d_in[14];
  const float* beta     = (const float*)d_in[15];

  float* out0 = (float*)d_out;                          // gelu(h'): B*N*OUTF
  float* out1 = out0 + (size_t)B_ * N_ * OUTF_;         // attention: B*N*N

  float* ws    = (float*)d_ws;
  float* scal  = ws;                    // 32 floats
  float* lposv = ws + 32;               // B*N
  float* rposv = lposv + B_ * N_;
  float* lnegv = rposv + B_ * N_;
  float* rnegv = lnegv + B_ * N_;
  unsigned short* WhvT = (unsigned short*)(rnegv + B_ * N_);   // [B][OUTF][N] bf16

  scalars_kernel<<<1, 64, 0, stream>>>(rel_emb, a_rel_p, a_rel_n, ll1, lr1, ll2, lr2, scal);
  wh_dots_kernel<<<(B_ * N_) / 16, 256, 0, stream>>>(h, W, alp, arp, aln, arn,
                                                     WhvT, lposv, rposv, lnegv, rnegv);
  fused_attn_pv<<<B_ * (N_ / 16), 512, 0, stream>>>(adj, lposv, rposv, lnegv, rnegv,
                                                    scal, WhvT, gamma, beta, out0, out1);
}

// Round 18
// 81.970 us; speedup vs baseline: 1.1730x; 1.0905x over previous
//
#include <hip/hip_runtime.h>
#include <math.h>

typedef short bf16x8 __attribute__((ext_vector_type(8)));
typedef float f32x4  __attribute__((ext_vector_type(4)));

constexpr int   B_    = 4;
constexpr int   N_    = 2048;
constexpr int   INF_  = 256;
constexpr int   OUTF_ = 128;
constexpr float LAMBDA_INIT_ = 0.35550906759096926f;
constexpr float OUT_SCALE_   = 0.64449093240903074f;   // 1 - LAMBDA_INIT
constexpr float EPS_         = 1e-5f;
constexpr float LOG2E_       = 1.44269504088896340736f;

__device__ inline unsigned short f2bf(float x) {
  unsigned u = __float_as_uint(x);
  u += 0x7fffu + ((u >> 16) & 1u);          // round-to-nearest-even
  return (unsigned short)(u >> 16);
}
__device__ inline unsigned pack2(float a, float b) {
  return (unsigned)f2bf(a) | ((unsigned)f2bf(b) << 16);
}

// ---------------- Kernel A: tiny scalars (rel scores + lambda), log2e-scaled ----------------
__global__ void scalars_kernel(const float* __restrict__ rel_emb,
                               const float* __restrict__ a_rel_pos,
                               const float* __restrict__ a_rel_neg,
                               const float* __restrict__ ll1, const float* __restrict__ lr1,
                               const float* __restrict__ ll2, const float* __restrict__ lr2,
                               float* __restrict__ scal) {
  int lane = threadIdx.x;  // 64 threads, 1 wave
  float p1 = ll1[lane] * lr1[lane];
  float p2 = ll2[lane] * lr2[lane];
  #pragma unroll
  for (int off = 32; off; off >>= 1) { p1 += __shfl_xor(p1, off); p2 += __shfl_xor(p2, off); }
  if (lane == 0) scal[12] = expf(p1) - expf(p2) + LAMBDA_INIT_;   // lam: NOT scaled
  if (lane < 6) {
    float sp = 0.f, sn = 0.f;
    for (int k = 0; k < 10; ++k) {
      float rv = rel_emb[lane * 10 + k];
      sp += rv * a_rel_pos[k];
      sn += rv * a_rel_neg[k];
    }
    scal[lane]     = sp * LOG2E_;
    scal[6 + lane] = sn * LOG2E_;
  }
}

// ---------------- Kernel B: Wh GEMM (4x4 register-blocked) + bf16 T-copy + fused dots ----------------
// 256 blocks x 256 threads; tile = 32 rows x 128 ch. Thread (rg = t>>5, cg = t&31):
// rows rg*4..+3, cols cg*4..+3, acc[4][4]. hT[row][k] broadcast ds_reads (conflict-free),
// W float4 coalesced. DS ops/thread: 512 -> 256 at 4x output/thread (4x less DS/CU).
__global__ __launch_bounds__(256) void wh_dots_v2(
    const float* __restrict__ h, const float* __restrict__ W,
    const float* __restrict__ alp, const float* __restrict__ arp,
    const float* __restrict__ aln, const float* __restrict__ arn,
    unsigned short* __restrict__ WhvT,
    float* __restrict__ lposv, float* __restrict__ rposv,
    float* __restrict__ lnegv, float* __restrict__ rnegv) {
  __shared__ __align__(16) float hT[32][260];   // [row][k], pad 260 (1040B, 16B-aligned rows)
  const int t = threadIdx.x;
  const int row0 = blockIdx.x * 32;
  const int b = row0 >> 11;

  // stage: thread t owns k=t for all 32 rows (coalesced global, conflict-free LDS writes)
  #pragma unroll 8
  for (int i = 0; i < 32; ++i) hT[i][t] = h[(size_t)(row0 + i) * INF_ + t];
  __syncthreads();

  const int rg = t >> 5;        // 0..7 -> rows rg*4..+3
  const int cg = t & 31;        // cols cg*4..+3
  const int c0 = cg * 4;
  float acc[4][4] = {{0.f,0.f,0.f,0.f},{0.f,0.f,0.f,0.f},{0.f,0.f,0.f,0.f},{0.f,0.f,0.f,0.f}};

  #pragma unroll 2
  for (int k4 = 0; k4 < 64; ++k4) {
    float4 hv[4], wv[4];
    #pragma unroll
    for (int rr = 0; rr < 4; ++rr)
      hv[rr] = *reinterpret_cast<const float4*>(&hT[rg * 4 + rr][k4 * 4]);
    #pragma unroll
    for (int j = 0; j < 4; ++j)
      wv[j] = *reinterpret_cast<const float4*>(&W[(size_t)(k4 * 4 + j) * OUTF_ + c0]);
    #pragma unroll
    for (int rr = 0; rr < 4; ++rr) {
      const float* hp = reinterpret_cast<const float*>(&hv[rr]);
      #pragma unroll
      for (int j = 0; j < 4; ++j) {
        const float* wp = reinterpret_cast<const float*>(&wv[j]);
        acc[rr][0] += hp[j] * wp[0];
        acc[rr][1] += hp[j] * wp[1];
        acc[rr][2] += hp[j] * wp[2];
        acc[rr][3] += hp[j] * wp[3];
      }
    }
  }

  // ---- WhvT bf16 transposed store: per col, 4 consecutive n (8B)
  const int n0 = (row0 & 2047) + rg * 4;
  #pragma unroll
  for (int cc = 0; cc < 4; ++cc) {
    uint2 v;
    v.x = pack2(acc[0][cc], acc[1][cc]);
    v.y = pack2(acc[2][cc], acc[3][cc]);
    *reinterpret_cast<uint2*>(WhvT + ((size_t)b * OUTF_ + c0 + cc) * N_ + n0) = v;
  }

  // ---- fused dots: 16-lane col-groups (lanes cg 0-15 = pos cols 0-63, 16-31 = neg)
  float aL[4], aR[4];
  #pragma unroll
  for (int cc = 0; cc < 4; ++cc) {
    const int c = c0 + cc;
    aL[cc] = (c < 64) ? alp[c] : aln[c - 64];
    aR[cc] = (c < 64) ? arp[c] : arn[c - 64];
  }
  float sl[4], sr2[4];
  #pragma unroll
  for (int rr = 0; rr < 4; ++rr) {
    sl[rr]  = (acc[rr][0] * aL[0] + acc[rr][1] * aL[1]) + (acc[rr][2] * aL[2] + acc[rr][3] * aL[3]);
    sr2[rr] = (acc[rr][0] * aR[0] + acc[rr][1] * aR[1]) + (acc[rr][2] * aR[2] + acc[rr][3] * aR[3]);
  }
  #pragma unroll
  for (int off = 1; off <= 8; off <<= 1) {
    #pragma unroll
    for (int rr = 0; rr < 4; ++rr) {
      sl[rr]  += __shfl_xor(sl[rr],  off);
      sr2[rr] += __shfl_xor(sr2[rr], off);
    }
  }
  if (cg == 0) {
    #pragma unroll
    for (int rr = 0; rr < 4; ++rr) {
      const int node = row0 + rg * 4 + rr;
      lposv[node] = sl[rr]  * LOG2E_;
      rposv[node] = sr2[rr] * LOG2E_;
    }
  } else if (cg == 16) {
    #pragma unroll
    for (int rr = 0; rr < 4; ++rr) {
      const int node = row0 + rg * 4 + rr;
      lnegv[node] = sl[rr]  * LOG2E_;
      rnegv[node] = sr2[rr] * LOG2E_;
    }
  }
}

// ---------------- Kernel D: fused attention + PV(MFMA) + LN + GELU (r17-passing, unchanged) ----------------
__global__ __launch_bounds__(512, 4) void fused_attn_pv(
    const int* __restrict__ adj,
    const float* __restrict__ lposv, const float* __restrict__ rposv,
    const float* __restrict__ lnegv, const float* __restrict__ rnegv,
    const float* __restrict__ scal, const unsigned short* __restrict__ WhvT,
    const float* __restrict__ gamma, const float* __restrict__ beta,
    float* __restrict__ out0, float* __restrict__ out1) {
  __shared__ __align__(16) uint4 A4[16 * 256];                  // 64KB A-tile
  float* scr = reinterpret_cast<float*>(&A4[15 * 256]);         // sums scratch (row-15 tail)
  float (*hp)[132] = reinterpret_cast<float (*)[132]>(A4);      // epilogue overlay

  const int t = threadIdx.x;
  const int lane = t & 63;
  const int wv = t >> 6;
  const int bi = blockIdx.x;
  const int b  = bi >> 7;
  const int i0 = (bi & 127) * 16;
  const int flat0 = b * N_ + i0;

  const float lam = scal[12];
  float srcP = -1.0e30f, srcN = -1.0e30f;
  if (lane >= 1 && lane <= 5) { srcP = scal[lane]; srcN = scal[6 + lane]; }
  const int iSrcP = __float_as_int(srcP);
  const int iSrcN = __float_as_int(srcN);

  const int j0 = t * 4;
  float4 rp4 = *reinterpret_cast<const float4*>(rposv + b * N_ + j0);
  float4 rn4 = *reinterpret_cast<const float4*>(rnegv + b * N_ + j0);
  const float rp[4] = {rp4.x, rp4.y, rp4.z, rp4.w};
  const float rn[4] = {rn4.x, rn4.y, rn4.z, rn4.w};

  const int wchunk = (t >> 1) >> 5;
  const int wloc   = (t >> 1) & 31;

  int4 avN = *reinterpret_cast<const int4*>(adj + (size_t)flat0 * N_ + j0);

  for (int r = 0; r < 16; ++r) {
    const int flat = flat0 + r;
    const int4 av4 = avN;
    if (r < 15)
      avN = *reinterpret_cast<const int4*>(adj + (size_t)(flat + 1) * N_ + j0);
    const float lP = lposv[flat];
    const float lN = lnegv[flat];
    int av[4] = {av4.x, av4.y, av4.z, av4.w};

    float p[4], n[4];
    #pragma unroll
    for (int q = 0; q < 4; ++q) {
      float rsp = __int_as_float(__builtin_amdgcn_ds_bpermute(av[q] << 2, iSrcP));
      float rsn = __int_as_float(__builtin_amdgcn_ds_bpermute(av[q] << 2, iSrcN));
      float e  = lP + rp[q] + rsp;
      float en = lN + rn[q] + rsn;
      e  = fmaxf(e, 0.2f * e);                 // leaky (pos scale commutes with log2e)
      en = fmaxf(en, 0.2f * en);
      p[q] = __builtin_amdgcn_exp2f(e);
      n[q] = __builtin_amdgcn_exp2f(en);
    }
    float sP = (p[0] + p[1]) + (p[2] + p[3]);
    float sN = (n[0] + n[1]) + (n[2] + n[3]);
    #pragma unroll
    for (int off = 32; off; off >>= 1) { sP += __shfl_xor(sP, off); sN += __shfl_xor(sN, off); }
    const int bf = r & 1;
    if (lane == 0) { scr[bf * 16 + wv] = sP; scr[bf * 16 + 8 + wv] = sN; }
    __syncthreads();
    float vP = scr[bf * 16 + (lane & 7)];
    vP += __shfl_xor(vP, 1); vP += __shfl_xor(vP, 2); vP += __shfl_xor(vP, 4);
    float vN = scr[bf * 16 + 8 + (lane & 7)];
    vN += __shfl_xor(vN, 1); vN += __shfl_xor(vN, 2); vN += __shfl_xor(vN, 4);
    const float s1 = 1.f / vP;
    const float s2 = -lam / vN;

    float a[4];
    #pragma unroll
    for (int q = 0; q < 4; ++q) a[q] = p[q] * s1 + n[q] * s2;
    float* o1 = out1 + (size_t)flat * N_ + j0;
    *reinterpret_cast<float4*>(o1) = make_float4(a[0], a[1], a[2], a[3]);

    if (r == 15) __syncthreads();   // drain scr reads before row-15 region is overwritten
    const int uidx = r * 256 + wchunk * 32 + (wloc ^ (r & 7));
    uint2 val;
    val.x = pack2(a[0], a[1]); val.y = pack2(a[2], a[3]);
    reinterpret_cast<uint2*>(A4)[uidx * 2 + (t & 1)] = val;
  }
  __syncthreads();   // A-tile complete

  // ---------------- phase 2: MFMA over full K, A from LDS, B reg-prefetched ----------------
  const int bl  = lane & 15;   // A row / B ch within tile
  const int kg  = lane >> 4;   // k-group
  const int ch  = wv * 16 + bl;
  const unsigned short* Bp = WhvT + ((size_t)b * OUTF_ + ch) * N_ + kg * 8;
  f32x4 acc0 = {0.f, 0.f, 0.f, 0.f};   // even chunks
  f32x4 acc1 = {0.f, 0.f, 0.f, 0.f};   // odd chunks
  const int arow = bl * 256;
  const int aswz = bl & 7;

  bf16x8 bBuf[2][8];
  #pragma unroll
  for (int kk = 0; kk < 8; ++kk)
    bBuf[0][kk] = *reinterpret_cast<const bf16x8*>(Bp + kk * 32);

  #pragma unroll
  for (int c = 0; c < 8; ++c) {
    const int cur = c & 1;
    if (c < 7) {
      #pragma unroll
      for (int kk = 0; kk < 8; ++kk)
        bBuf[cur ^ 1][kk] = *reinterpret_cast<const bf16x8*>(Bp + (c + 1) * 256 + kk * 32);
    }
    #pragma unroll
    for (int kk = 0; kk < 8; ++kk) {
      bf16x8 a = *reinterpret_cast<const bf16x8*>(&A4[arow + c * 32 + ((kk * 4 + kg) ^ aswz)]);
      if (cur == 0) acc0 = __builtin_amdgcn_mfma_f32_16x16x32_bf16(a, bBuf[0][kk], acc0, 0, 0, 0);
      else          acc1 = __builtin_amdgcn_mfma_f32_16x16x32_bf16(a, bBuf[1][kk], acc1, 0, 0, 0);
    }
  }
  __syncthreads();   // all A reads done; overlay hp

  #pragma unroll
  for (int q = 0; q < 4; ++q) hp[kg * 4 + q][ch] = acc0[q] + acc1[q];
  __syncthreads();

  const int row = t >> 5;
  const int c0  = t & 31;
  float v[4], s = 0.f, sq = 0.f;
  #pragma unroll
  for (int e = 0; e < 4; ++e) {
    v[e] = hp[row][c0 + e * 32];
    s += v[e]; sq += v[e] * v[e];
  }
  #pragma unroll
  for (int off = 16; off; off >>= 1) { s += __shfl_xor(s, off); sq += __shfl_xor(sq, off); }
  const float mu  = s  * (1.f / 128.f);
  const float var = sq * (1.f / 128.f) - mu * mu;
  const float inv = rsqrtf(var + EPS_);
  float* orow = out0 + ((size_t)(b * N_ + i0 + row)) * OUTF_;
  #pragma unroll
  for (int e = 0; e < 4; ++e) {
    const int chh = c0 + e * 32;
    float y = (v[e] - mu) * inv * gamma[chh] + beta[chh];
    y *= OUT_SCALE_;
    orow[chh] = 0.5f * y * (1.f + erff(y * 0.70710678118654752f));
  }
}

extern "C" void kernel_launch(void* const* d_in, const int* in_sizes, int n_in,
                              void* d_out, int out_size, void* d_ws, size_t ws_size,
                              hipStream_t stream) {
  (void)in_sizes; (void)n_in; (void)out_size; (void)ws_size;
  const float* h        = (const float*)d_in[0];
  const int*   adj      = (const int*)d_in[1];
  const float* W        = (const float*)d_in[2];
  const float* alp      = (const float*)d_in[3];
  const float* arp      = (const float*)d_in[4];
  const float* aln      = (const float*)d_in[5];
  const float* arn      = (const float*)d_in[6];
  const float* rel_emb  = (const float*)d_in[7];
  const float* a_rel_p  = (const float*)d_in[8];
  const float* a_rel_n  = (const float*)d_in[9];
  const float* ll1      = (const float*)d_in[10];
  const float* lr1      = (const float*)d_in[11];
  const float* ll2      = (const float*)d_in[12];
  const float* lr2      = (const float*)d_in[13];
  const float* gamma    = (const float*)d_in[14];
  const float* beta     = (const float*)d_in[15];

  float* out0 = (float*)d_out;                          // gelu(h'): B*N*OUTF
  float* out1 = out0 + (size_t)B_ * N_ * OUTF_;         // attention: B*N*N

  float* ws    = (float*)d_ws;
  float* scal  = ws;                    // 32 floats
  float* lposv = ws + 32;               // B*N
  float* rposv = lposv + B_ * N_;
  float* lnegv = rposv + B_ * N_;
  float* rnegv = lnegv + B_ * N_;
  unsigned short* WhvT = (unsigned short*)(rnegv + B_ * N_);   // [B][OUTF][N] bf16

  scalars_kernel<<<1, 64, 0, stream>>>(rel_emb, a_rel_p, a_rel_n, ll1, lr1, ll2, lr2, scal);
  wh_dots_v2<<<(B_ * N_) / 32, 256, 0, stream>>>(h, W, alp, arp, aln, arn,
                                                 WhvT, lposv, rposv, lnegv, rnegv);
  fused_attn_pv<<<B_ * (N_ / 16), 512, 0, stream>>>(adj, lposv, rposv, lnegv, rnegv,
                                                    scal, WhvT, gamma, beta, out0, out1);
}